// Round 1
// baseline (1866.063 us; speedup 1.0000x reference)
//
#include <hip/hip_runtime.h>
#include <cstdint>
#include <cstddef>

#define IMG 512
#define JD 192

// ---------------------------------------------------------------------------
// K1: partial Gram. grid (4 patch-chunks, 4 row-slabs, 16 batches), 256 thr.
// part[b][slab][chunk][48*192] = sum over 1024 patches of A[:,r]*A[:,c]
// ---------------------------------------------------------------------------
__global__ __launch_bounds__(256) void k_gram(const float* __restrict__ x,
                                              float* __restrict__ part) {
  const int ck = blockIdx.x;
  const int sl = blockIdx.y;
  const int b  = blockIdx.z;
  const int t  = threadIdx.x;
  __shared__ float tile[32][JD];
  const int ty = t >> 5;          // 8 groups of 6 rows (slab of 48)
  const int tx = t & 31;          // 32 groups of 6 cols (192)
  const int r0 = sl*48 + ty*6;
  const int c0 = tx*6;
  float acc[6][6];
#pragma unroll
  for (int i=0;i<6;i++)
#pragma unroll
    for (int j=0;j<6;j++) acc[i][j]=0.f;
  const float* xb = x + (size_t)b*3*IMG*IMG;
  const int nbeg = ck*1024;
  for (int n0 = nbeg; n0 < nbeg+1024; n0 += 32) {
    for (int f = t; f < 32*JD; f += 256) {
      const int nl = f / JD, j = f - nl*JD;
      const int n = n0 + nl;
      const int hh = n >> 6, ww = n & 63;
      const int c = j >> 6, p = (j >> 3) & 7, q = j & 7;
      tile[nl][j] = xb[(c*IMG + hh*8+p)*IMG + ww*8 + q];
    }
    __syncthreads();
#pragma unroll 4
    for (int nl = 0; nl < 32; nl++) {
      float va[6], vb[6];
#pragma unroll
      for (int i=0;i<6;i++) va[i] = tile[nl][r0+i];
#pragma unroll
      for (int j=0;j<6;j++) vb[j] = tile[nl][c0+j];
#pragma unroll
      for (int i=0;i<6;i++)
#pragma unroll
        for (int j=0;j<6;j++) acc[i][j] += va[i]*vb[j];
    }
    __syncthreads();
  }
  float* dst = part + (((size_t)(b*4 + sl))*4 + ck) * (size_t)(48*JD);
#pragma unroll
  for (int i=0;i<6;i++)
#pragma unroll
    for (int j=0;j<6;j++)
      dst[(ty*6+i)*JD + c0+j] = acc[i][j];
}

// ---------------------------------------------------------------------------
// K2: reduce 4 chunk-partials -> Gs = G / 4096 (scaled Gram)
// ---------------------------------------------------------------------------
__global__ __launch_bounds__(256) void k_greduce(const float* __restrict__ part,
                                                 float* __restrict__ Gs) {
  const int idx = blockIdx.x*256 + threadIdx.x;   // 16*36864 total
  const int b = idx / (JD*JD);
  const int e = idx - b*(JD*JD);
  const int r = e / JD;
  const int sl = r / 48;
  const int w = (r - sl*48)*JD + (e - r*JD);
  const float* p = part + ((size_t)(b*4+sl))*4*(48*JD) + w;
  float s = 0.f;
#pragma unroll
  for (int ck=0; ck<4; ck++) s += p[(size_t)ck*48*JD];
  Gs[idx] = s * (1.0f/4096.0f);
}

// ---------------------------------------------------------------------------
// K3: D = S*S for symmetric S (per batch).  C[i][j] = sum_k S[i][k]*S[j][k].
// grid (6 lower-tri 64x64 tile-pairs, 16 batches); mirrors written.
// ---------------------------------------------------------------------------
__global__ __launch_bounds__(256) void k_sq(const float* __restrict__ S,
                                            float* __restrict__ D) {
  const int tp = blockIdx.x;
  const int b  = blockIdx.y;
  int ti, tj;
  if      (tp==0){ti=0;tj=0;} else if (tp==1){ti=1;tj=0;}
  else if (tp==2){ti=1;tj=1;} else if (tp==3){ti=2;tj=0;}
  else if (tp==4){ti=2;tj=1;} else            {ti=2;tj=2;}
  const float* Sb = S + (size_t)b*JD*JD;
  float* Db = D + (size_t)b*JD*JD;
  __shared__ float Ar[64][33];
  __shared__ float Br[64][33];
  const int t = threadIdx.x;
  const int ty = t >> 4, tx = t & 15;
  float acc[4][4];
#pragma unroll
  for (int i=0;i<4;i++)
#pragma unroll
    for (int j=0;j<4;j++) acc[i][j]=0.f;
  for (int k0=0; k0<JD; k0+=32) {
    for (int f=t; f<2048; f+=256) {
      const int row = f >> 5, kk = f & 31;
      Ar[row][kk] = Sb[(ti*64+row)*JD + k0+kk];
      Br[row][kk] = Sb[(tj*64+row)*JD + k0+kk];
    }
    __syncthreads();
#pragma unroll 4
    for (int k=0;k<32;k++) {
      float va[4], vb[4];
#pragma unroll
      for (int i=0;i<4;i++) va[i] = Ar[ty*4+i][k];
#pragma unroll
      for (int j=0;j<4;j++) vb[j] = Br[tx*4+j][k];
#pragma unroll
      for (int i=0;i<4;i++)
#pragma unroll
        for (int j=0;j<4;j++) acc[i][j] += va[i]*vb[j];
    }
    __syncthreads();
  }
#pragma unroll
  for (int i=0;i<4;i++)
#pragma unroll
    for (int j=0;j<4;j++) {
      const int r = ti*64+ty*4+i, c = tj*64+tx*4+j;
      Db[r*JD+c] = acc[i][j];
      if (ti != tj) Db[c*JD+r] = acc[i][j];
    }
}

// ---------------------------------------------------------------------------
// K4 helpers (per-batch block, 256 threads)
// ---------------------------------------------------------------------------
__device__ inline void dev_stage_slab(const float* __restrict__ src, float* sl,
                                      int base, int t) {
  for (int f = t; f < 2048; f += 256) sl[f] = src[(base + (f>>6))*64 + (f&63)];
}

// Wout(192x64) = G(192x192) * Win(192x64)
__device__ void dev_matmul(const float* __restrict__ G, const float* __restrict__ Win,
                           float* __restrict__ Wout, float* sla, int t) {
  const int rg = t >> 2, cg = t & 3;
  float acc[3][16];
#pragma unroll
  for (int i=0;i<3;i++)
#pragma unroll
    for (int j=0;j<16;j++) acc[i][j]=0.f;
  for (int k0=0; k0<JD; k0+=32) {
    dev_stage_slab(Win, sla, k0, t);
    __syncthreads();
#pragma unroll 4
    for (int k=0;k<32;k++) {
      const float a0 = G[(rg*3+0)*JD + k0+k];
      const float a1 = G[(rg*3+1)*JD + k0+k];
      const float a2 = G[(rg*3+2)*JD + k0+k];
#pragma unroll
      for (int j=0;j<16;j++) {
        const float bb = sla[k*64 + cg*16 + j];
        acc[0][j] += a0*bb; acc[1][j] += a1*bb; acc[2][j] += a2*bb;
      }
    }
    __syncthreads();
  }
#pragma unroll
  for (int i=0;i<3;i++)
#pragma unroll
    for (int j=0;j<16;j++)
      Wout[(rg*3+i)*64 + cg*16 + j] = acc[i][j];
  __syncthreads();
}

// In-place ridge-CholQR of W (192x64).  S1 is 64x68 LDS scratch.
__device__ void dev_orth(float* __restrict__ W, float* S1, float* sla,
                         float* rdv, float* misc, int t, float ridge) {
  const int ty = t >> 4, tx = t & 15;
  float acc[4][4];
#pragma unroll
  for (int i=0;i<4;i++)
#pragma unroll
    for (int j=0;j<4;j++) acc[i][j]=0.f;
  for (int r0=0; r0<JD; r0+=32) {
    dev_stage_slab(W, sla, r0, t);
    __syncthreads();
#pragma unroll 4
    for (int rl=0;rl<32;rl++) {
      float va[4], vb[4];
#pragma unroll
      for (int i=0;i<4;i++) va[i] = sla[rl*64 + ty*4+i];
#pragma unroll
      for (int j=0;j<4;j++) vb[j] = sla[rl*64 + tx*4+j];
#pragma unroll
      for (int i=0;i<4;i++)
#pragma unroll
        for (int j=0;j<4;j++) acc[i][j] += va[i]*vb[j];
    }
    __syncthreads();
  }
#pragma unroll
  for (int i=0;i<4;i++)
#pragma unroll
    for (int j=0;j<4;j++)
      S1[(ty*4+i)*68 + tx*4+j] = acc[i][j];
  __syncthreads();
  if (ridge > 0.f) {
    if (t == 0) {
      float m = 0.f;
      for (int j=0;j<64;j++) m = fmaxf(m, S1[j*68+j]);
      misc[0] = m * ridge;
    }
    __syncthreads();
    if (t < 64) S1[t*68+t] += misc[0];
    __syncthreads();
  }
  // Cholesky, lazy-unscaled columns (scale at the end)
  for (int j=0;j<63;j++) {
    __syncthreads();
    const float invd = 1.0f / S1[j*68+j];
    const int wd = 63 - j;
    for (int f=t; f<wd*64; f+=256) {
      const int i = j+1 + (f>>6);
      const int k = f & 63;
      if (k > j && k <= i)
        S1[i*68+k] -= S1[i*68+j]*S1[k*68+j]*invd;
    }
  }
  __syncthreads();
  if (t < 64) rdv[t] = rsqrtf(S1[t*68+t]);   // rdv[c] = 1/L[c][c]
  __syncthreads();
  for (int f=t; f<64*64; f+=256) {
    const int i = f>>6, k = f&63;
    if (k < i) S1[i*68+k] *= rdv[k];
  }
  __syncthreads();
  // W <- W * L^{-T} via per-row back-substitution (row resident in regs)
  if (t < JD) {
    float w[64];
#pragma unroll
    for (int c=0;c<64;c++) w[c] = W[t*64+c];
#pragma unroll
    for (int c=0;c<64;c++) {
      float v = w[c];
#pragma unroll
      for (int k=0;k<c;k++) v -= w[k]*S1[c*68+k];
      w[c] = v * rdv[c];
    }
#pragma unroll
    for (int c=0;c<64;c++) W[t*64+c] = w[c];
  }
  __syncthreads();
}

// S1(64x64, stride 68) = X^T * Y  (both 192x64 global)
__device__ void dev_hgemm(const float* __restrict__ X, const float* __restrict__ Y,
                          float* S1, float* sla, float* slb, int t) {
  const int ty = t >> 4, tx = t & 15;
  float acc[4][4];
#pragma unroll
  for (int i=0;i<4;i++)
#pragma unroll
    for (int j=0;j<4;j++) acc[i][j]=0.f;
  for (int r0=0; r0<JD; r0+=32) {
    dev_stage_slab(X, sla, r0, t);
    dev_stage_slab(Y, slb, r0, t);
    __syncthreads();
#pragma unroll 4
    for (int rl=0;rl<32;rl++) {
      float va[4], vb[4];
#pragma unroll
      for (int i=0;i<4;i++) va[i] = sla[rl*64 + ty*4+i];
#pragma unroll
      for (int j=0;j<4;j++) vb[j] = slb[rl*64 + tx*4+j];
#pragma unroll
      for (int i=0;i<4;i++)
#pragma unroll
        for (int j=0;j<4;j++) acc[i][j] += va[i]*vb[j];
    }
    __syncthreads();
  }
#pragma unroll
  for (int i=0;i<4;i++)
#pragma unroll
    for (int j=0;j<4;j++)
      S1[(ty*4+i)*68 + tx*4+j] = acc[i][j];
  __syncthreads();
}

// ---------------------------------------------------------------------------
// K4: per-batch eigen stage. grid 16, 256 threads.
// subspace iteration (G16) + CholQR -> Rayleigh-Ritz H -> Jacobi -> M = V V^T
// ---------------------------------------------------------------------------
__global__ __launch_bounds__(256) void k_eig(const float* __restrict__ G16,
                                             const float* __restrict__ Gs,
                                             float* __restrict__ WaG,
                                             float* __restrict__ WbG,
                                             float* __restrict__ Mg) {
  const int b = blockIdx.x;
  const int t = threadIdx.x;
  __shared__ float S1[64*68];
  __shared__ float S2[192*33];   // Yt (stride 68) then V-stage (stride 33)
  __shared__ float sla[2048];
  __shared__ float slb[2048];
  __shared__ float rdv[64];
  __shared__ float csv[64];
  __shared__ float dval[64];
  __shared__ float misc[4];
  __shared__ int pa[32], pb[32], sel[32];

  const float* G16b = G16 + (size_t)b*JD*JD;
  const float* Gsb  = Gs  + (size_t)b*JD*JD;
  float* cur = WaG + (size_t)b*JD*64;
  float* oth = WbG + (size_t)b*JD*64;
  float* Mb  = Mg  + (size_t)b*JD*JD;

  // W0 = first 64 columns of G16 (= G16 * E64)
  for (int f=t; f<JD*64; f+=256)
    cur[f] = G16b[(f>>6)*JD + (f&63)];
  __syncthreads();
  dev_orth(cur, S1, sla, rdv, misc, t, 1e-6f);

  for (int it=0; it<3; it++) {
    dev_matmul(G16b, cur, oth, sla, t);
    dev_orth(oth, S1, sla, rdv, misc, t, 1e-6f);
    float* tmp = cur; cur = oth; oth = tmp;
  }
  dev_orth(cur, S1, sla, rdv, misc, t, 0.f);   // CholQR pass 2 (clean)

  dev_matmul(Gsb, cur, oth, sla, t);           // T = Gs*W -> oth
  dev_hgemm(cur, oth, S1, sla, slb, t);        // H = W^T T -> S1

  // Yt = I
  for (int f=t; f<64*68; f+=256) S2[f] = 0.f;
  __syncthreads();
  if (t < 64) S2[t*68+t] = 1.f;
  __syncthreads();

  // cyclic parallel Jacobi, round-robin pairing
  for (int sweep=0; sweep<7; sweep++) {
    for (int r=0; r<63; r++) {
      if (t < 32) {
        const int k = t;
        const int a  = (k==0) ? 0 : ((k-1+r) % 63) + 1;
        const int bb = ((62 - k + r) % 63) + 1;
        pa[t] = a; pb[t] = bb;
        const float app = S1[a*68+a], aqq = S1[bb*68+bb], apq = S1[a*68+bb];
        float c, s;
        if (fabsf(apq) > 1e-20f) {
          const float tau = (aqq - app) / (2.f*apq);
          const float tt = (tau >= 0.f ? 1.f : -1.f) / (fabsf(tau) + sqrtf(1.f + tau*tau));
          c = 1.f / sqrtf(1.f + tt*tt);
          s = tt * c;
        } else { c = 1.f; s = 0.f; }
        csv[2*t] = c; csv[2*t+1] = s;
      }
      __syncthreads();
      { // rows of H and Yt  (J^T from the left)
        const int pr = t >> 3, ch = t & 7;
        const int a = pa[pr], bb = pb[pr];
        const float c = csv[2*pr], s = csv[2*pr+1];
        const int k0 = ch*8;
#pragma unroll
        for (int k=0;k<8;k++) {
          const float xp = S1[a*68+k0+k], xq = S1[bb*68+k0+k];
          S1[a*68+k0+k]  = c*xp - s*xq;
          S1[bb*68+k0+k] = s*xp + c*xq;
          const float yp = S2[a*68+k0+k], yq = S2[bb*68+k0+k];
          S2[a*68+k0+k]  = c*yp - s*yq;
          S2[bb*68+k0+k] = s*yp + c*yq;
        }
      }
      __syncthreads();
      { // columns of H (J from the right) — row-major access
        const int row = t >> 2, qr = t & 3;
#pragma unroll
        for (int m8=0;m8<8;m8++) {
          const int m = qr*8 + m8;
          const int a = pa[m], bb = pb[m];
          const float c = csv[2*m], s = csv[2*m+1];
          const float xx = S1[row*68+a], yy = S1[row*68+bb];
          S1[row*68+a]  = c*xx - s*yy;
          S1[row*68+bb] = s*xx + c*yy;
        }
      }
      __syncthreads();
    }
  }

  // top-32 selection by eigenvalue rank
  if (t < 64) dval[t] = S1[t*68+t];
  __syncthreads();
  if (t < 64) {
    int rank = 0;
    for (int k=0;k<64;k++) {
      const float dk = dval[k];
      if (dk > dval[t] || (dk == dval[t] && k < t)) rank++;
    }
    if (rank < 32) sel[rank] = t;
  }
  __syncthreads();

  // V(192x32) = W * Y[:,sel]  (eigvec j = row sel[j] of Yt)
  for (int f=t; f<JD*32; f+=256) {
    const int r = f >> 5, i = f & 31;
    const int sj = sel[i];
    float a0 = 0.f;
#pragma unroll 8
    for (int a=0;a<64;a++) a0 += cur[r*64+a] * S2[sj*68+a];
    oth[r*32+i] = a0;
  }
  __syncthreads();
  // stage V into LDS [192][33]
  for (int f=t; f<JD*32; f+=256)
    S2[(f>>5)*33 + (f&31)] = oth[f];
  __syncthreads();
  // M = V V^T  (192x192) -> global
  for (int tt=t; tt<576; tt+=256) {
    const int tr = tt/24, tc = tt - tr*24;
    const int r0 = tr*8, c0 = tc*8;
    float acc2[8][8];
#pragma unroll
    for (int i=0;i<8;i++)
#pragma unroll
      for (int j=0;j<8;j++) acc2[i][j]=0.f;
    for (int k=0;k<32;k++) {
      float va[8], vb[8];
#pragma unroll
      for (int i=0;i<8;i++) va[i] = S2[(r0+i)*33+k];
#pragma unroll
      for (int j=0;j<8;j++) vb[j] = S2[(c0+j)*33+k];
#pragma unroll
      for (int i=0;i<8;i++)
#pragma unroll
        for (int j=0;j<8;j++) acc2[i][j] += va[i]*vb[j];
    }
#pragma unroll
    for (int i=0;i<8;i++)
#pragma unroll
      for (int j=0;j<8;j++)
        Mb[(r0+i)*JD + c0+j] = acc2[i][j];
  }
}

// ---------------------------------------------------------------------------
// K5: recon = A * M, fused depatchify. grid (128 patch-blocks, 16 batches).
// ---------------------------------------------------------------------------
__global__ __launch_bounds__(256) void k_recon(const float* __restrict__ x,
                                               const float* __restrict__ Mg,
                                               float* __restrict__ out) {
  const int nb = blockIdx.x;
  const int b  = blockIdx.y;
  const int t  = threadIdx.x;
  __shared__ float At[32][17];
  __shared__ float Mt[16][JD];
  const float* xb = x + (size_t)b*3*IMG*IMG;
  const float* Mb = Mg + (size_t)b*JD*JD;
  float* ob = out + (size_t)b*3*IMG*IMG;
  const int pg = t >> 4;   // 16 groups x 2 patches
  const int jg = t & 15;   // 16 groups x 12 jout
  float acc[2][12];
#pragma unroll
  for (int i=0;i<2;i++)
#pragma unroll
    for (int j=0;j<12;j++) acc[i][j]=0.f;
  for (int j0=0; j0<JD; j0+=16) {
    for (int f=t; f<512; f+=256) {
      const int nl = f >> 4, jj = f & 15;
      const int j = j0 + jj;
      const int n = nb*32 + nl;
      const int hh = n >> 6, ww = n & 63;
      const int c = j >> 6, p = (j >> 3) & 7, q = j & 7;
      At[nl][jj] = xb[(c*IMG + hh*8+p)*IMG + ww*8 + q];
    }
    for (int f=t; f<3072; f+=256) {
      const int jj = f / JD, cc = f - jj*JD;
      Mt[jj][cc] = Mb[(j0+jj)*JD + cc];
    }
    __syncthreads();
#pragma unroll 4
    for (int jj=0;jj<16;jj++) {
      const float a0 = At[pg*2+0][jj];
      const float a1 = At[pg*2+1][jj];
#pragma unroll
      for (int j=0;j<12;j++) {
        const float mm = Mt[jj][jg*12+j];
        acc[0][j] += a0*mm;
        acc[1][j] += a1*mm;
      }
    }
    __syncthreads();
  }
#pragma unroll
  for (int i=0;i<2;i++) {
    const int n = nb*32 + pg*2 + i;
    const int hh = n >> 6, ww = n & 63;
#pragma unroll
    for (int j4=0;j4<3;j4++) {
      const int jo = jg*12 + j4*4;
      const int c = jo >> 6, p = (jo >> 3) & 7, q = jo & 7;
      const float4 v = make_float4(acc[i][j4*4+0], acc[i][j4*4+1],
                                   acc[i][j4*4+2], acc[i][j4*4+3]);
      *(float4*)(ob + (size_t)(c*IMG + hh*8+p)*IMG + ww*8 + q) = v;
    }
  }
}

// ---------------------------------------------------------------------------
// Workspace layout (floats):
//   [0 .. 2,359,296)        k_gram partials; later overlaid:
//                             M @ 0 (589,824), Wa @ 589,824, Wb @ 786,432
//   [2,359,296 .. )         Gs   (589,824)
//   [2,949,120 .. )         P0   (589,824)
//   [3,538,944 .. )         P1   (589,824)     total ~16.5 MB
// ---------------------------------------------------------------------------
extern "C" void kernel_launch(void* const* d_in, const int* in_sizes, int n_in,
                              void* d_out, int out_size, void* d_ws, size_t ws_size,
                              hipStream_t stream) {
  (void)in_sizes; (void)n_in; (void)out_size; (void)ws_size;
  const float* x = (const float*)d_in[0];
  float* out = (float*)d_out;
  float* ws  = (float*)d_ws;

  float* part = ws;
  float* Gs   = ws + 2359296;
  float* P0   = ws + 2949120;
  float* P1   = ws + 3538944;
  float* Mg   = ws;             // overlay (part dead after k_greduce)
  float* Wa   = ws + 589824;
  float* Wb   = ws + 786432;

  k_gram  <<<dim3(4,4,16), 256, 0, stream>>>(x, part);
  k_greduce<<<2304,        256, 0, stream>>>(part, Gs);
  k_sq    <<<dim3(6,16),   256, 0, stream>>>(Gs, P0);   // Gs^2
  k_sq    <<<dim3(6,16),   256, 0, stream>>>(P0, P1);   // Gs^4
  k_sq    <<<dim3(6,16),   256, 0, stream>>>(P1, P0);   // Gs^8
  k_sq    <<<dim3(6,16),   256, 0, stream>>>(P0, P1);   // Gs^16
  k_eig   <<<16,           256, 0, stream>>>(P1, Gs, Wa, Wb, Mg);
  k_recon <<<dim3(128,16), 256, 0, stream>>>(x, Mg, out);
}

// Round 2
// 1389.264 us; speedup vs baseline: 1.3432x; 1.3432x over previous
//
#include <hip/hip_runtime.h>
#include <cstdint>
#include <cstddef>

#define IMG 512
#define JD 192

// ---------------------------------------------------------------------------
// K1: partial Gram. grid (4 patch-chunks, 4 row-slabs, 16 batches), 256 thr.
// ---------------------------------------------------------------------------
__global__ __launch_bounds__(256) void k_gram(const float* __restrict__ x,
                                              float* __restrict__ part) {
  const int ck = blockIdx.x;
  const int sl = blockIdx.y;
  const int b  = blockIdx.z;
  const int t  = threadIdx.x;
  __shared__ float tile[32][JD];
  const int ty = t >> 5;
  const int tx = t & 31;
  const int r0 = sl*48 + ty*6;
  const int c0 = tx*6;
  float acc[6][6];
#pragma unroll
  for (int i=0;i<6;i++)
#pragma unroll
    for (int j=0;j<6;j++) acc[i][j]=0.f;
  const float* xb = x + (size_t)b*3*IMG*IMG;
  const int nbeg = ck*1024;
  for (int n0 = nbeg; n0 < nbeg+1024; n0 += 32) {
    for (int f = t; f < 32*JD; f += 256) {
      const int nl = f / JD, j = f - nl*JD;
      const int n = n0 + nl;
      const int hh = n >> 6, ww = n & 63;
      const int c = j >> 6, p = (j >> 3) & 7, q = j & 7;
      tile[nl][j] = xb[(c*IMG + hh*8+p)*IMG + ww*8 + q];
    }
    __syncthreads();
#pragma unroll 4
    for (int nl = 0; nl < 32; nl++) {
      float va[6], vb[6];
#pragma unroll
      for (int i=0;i<6;i++) va[i] = tile[nl][r0+i];
#pragma unroll
      for (int j=0;j<6;j++) vb[j] = tile[nl][c0+j];
#pragma unroll
      for (int i=0;i<6;i++)
#pragma unroll
        for (int j=0;j<6;j++) acc[i][j] += va[i]*vb[j];
    }
    __syncthreads();
  }
  float* dst = part + (((size_t)(b*4 + sl))*4 + ck) * (size_t)(48*JD);
#pragma unroll
  for (int i=0;i<6;i++)
#pragma unroll
    for (int j=0;j<6;j++)
      dst[(ty*6+i)*JD + c0+j] = acc[i][j];
}

// ---------------------------------------------------------------------------
// K2: reduce 4 chunk-partials -> Gs = G / 4096
// ---------------------------------------------------------------------------
__global__ __launch_bounds__(256) void k_greduce(const float* __restrict__ part,
                                                 float* __restrict__ Gs) {
  const int idx = blockIdx.x*256 + threadIdx.x;
  const int b = idx / (JD*JD);
  const int e = idx - b*(JD*JD);
  const int r = e / JD;
  const int sl = r / 48;
  const int w = (r - sl*48)*JD + (e - r*JD);
  const float* p = part + ((size_t)(b*4+sl))*4*(48*JD) + w;
  float s = 0.f;
#pragma unroll
  for (int ck=0; ck<4; ck++) s += p[(size_t)ck*48*JD];
  Gs[idx] = s * (1.0f/4096.0f);
}

// ---------------------------------------------------------------------------
// K3: D = S*S for symmetric S (per batch), lower-tri tile pairs.
// ---------------------------------------------------------------------------
__global__ __launch_bounds__(256) void k_sq(const float* __restrict__ S,
                                            float* __restrict__ D) {
  const int tp = blockIdx.x;
  const int b  = blockIdx.y;
  int ti, tj;
  if      (tp==0){ti=0;tj=0;} else if (tp==1){ti=1;tj=0;}
  else if (tp==2){ti=1;tj=1;} else if (tp==3){ti=2;tj=0;}
  else if (tp==4){ti=2;tj=1;} else            {ti=2;tj=2;}
  const float* Sb = S + (size_t)b*JD*JD;
  float* Db = D + (size_t)b*JD*JD;
  __shared__ float Ar[64][33];
  __shared__ float Br[64][33];
  const int t = threadIdx.x;
  const int ty = t >> 4, tx = t & 15;
  float acc[4][4];
#pragma unroll
  for (int i=0;i<4;i++)
#pragma unroll
    for (int j=0;j<4;j++) acc[i][j]=0.f;
  for (int k0=0; k0<JD; k0+=32) {
    for (int f=t; f<2048; f+=256) {
      const int row = f >> 5, kk = f & 31;
      Ar[row][kk] = Sb[(ti*64+row)*JD + k0+kk];
      Br[row][kk] = Sb[(tj*64+row)*JD + k0+kk];
    }
    __syncthreads();
#pragma unroll 4
    for (int k=0;k<32;k++) {
      float va[4], vb[4];
#pragma unroll
      for (int i=0;i<4;i++) va[i] = Ar[ty*4+i][k];
#pragma unroll
      for (int j=0;j<4;j++) vb[j] = Br[tx*4+j][k];
#pragma unroll
      for (int i=0;i<4;i++)
#pragma unroll
        for (int j=0;j<4;j++) acc[i][j] += va[i]*vb[j];
    }
    __syncthreads();
  }
#pragma unroll
  for (int i=0;i<4;i++)
#pragma unroll
    for (int j=0;j<4;j++) {
      const int r = ti*64+ty*4+i, c = tj*64+tx*4+j;
      Db[r*JD+c] = acc[i][j];
      if (ti != tj) Db[c*JD+r] = acc[i][j];
    }
}

// ---------------------------------------------------------------------------
// K4 helpers (per-batch block, 256 threads)
// ---------------------------------------------------------------------------
__device__ inline void dev_stage_slab(const float* __restrict__ src, float* sl,
                                      int base, int t) {
  for (int f = t; f < 2048; f += 256) sl[f] = src[(base + (f>>6))*64 + (f&63)];
}

// Wout(192x64) = G(192x192) * Win(192x64)
__device__ void dev_matmul(const float* __restrict__ G, const float* __restrict__ Win,
                           float* __restrict__ Wout, float* sla, int t) {
  const int rg = t >> 2, cg = t & 3;
  float acc[3][16];
#pragma unroll
  for (int i=0;i<3;i++)
#pragma unroll
    for (int j=0;j<16;j++) acc[i][j]=0.f;
  for (int k0=0; k0<JD; k0+=32) {
    dev_stage_slab(Win, sla, k0, t);
    __syncthreads();
#pragma unroll 4
    for (int k=0;k<32;k++) {
      const float a0 = G[(rg*3+0)*JD + k0+k];
      const float a1 = G[(rg*3+1)*JD + k0+k];
      const float a2 = G[(rg*3+2)*JD + k0+k];
#pragma unroll
      for (int j=0;j<16;j++) {
        const float bb = sla[k*64 + cg*16 + j];
        acc[0][j] += a0*bb; acc[1][j] += a1*bb; acc[2][j] += a2*bb;
      }
    }
    __syncthreads();
  }
#pragma unroll
  for (int i=0;i<3;i++)
#pragma unroll
    for (int j=0;j<16;j++)
      Wout[(rg*3+i)*64 + cg*16 + j] = acc[i][j];
  __syncthreads();
}

// In-place ridge-CholQR of W (192x64). S1 is 64x68 LDS scratch.
__device__ void dev_orth(float* __restrict__ W, float* S1, float* sla,
                         float* rdv, float* misc, int t, float ridge) {
  const int ty = t >> 4, tx = t & 15;
  float acc[4][4];
#pragma unroll
  for (int i=0;i<4;i++)
#pragma unroll
    for (int j=0;j<4;j++) acc[i][j]=0.f;
  for (int r0=0; r0<JD; r0+=32) {
    dev_stage_slab(W, sla, r0, t);
    __syncthreads();
#pragma unroll 4
    for (int rl=0;rl<32;rl++) {
      float va[4], vb[4];
#pragma unroll
      for (int i=0;i<4;i++) va[i] = sla[rl*64 + ty*4+i];
#pragma unroll
      for (int j=0;j<4;j++) vb[j] = sla[rl*64 + tx*4+j];
#pragma unroll
      for (int i=0;i<4;i++)
#pragma unroll
        for (int j=0;j<4;j++) acc[i][j] += va[i]*vb[j];
    }
    __syncthreads();
  }
#pragma unroll
  for (int i=0;i<4;i++)
#pragma unroll
    for (int j=0;j<4;j++)
      S1[(ty*4+i)*68 + tx*4+j] = acc[i][j];
  __syncthreads();
  if (ridge > 0.f) {
    if (t == 0) {
      float m = 0.f;
      for (int j=0;j<64;j++) m = fmaxf(m, S1[j*68+j]);
      misc[0] = m * ridge;
    }
    __syncthreads();
    if (t < 64) S1[t*68+t] += misc[0];
    __syncthreads();
  }
  for (int j=0;j<63;j++) {
    __syncthreads();
    const float invd = 1.0f / S1[j*68+j];
    const int wd = 63 - j;
    for (int f=t; f<wd*64; f+=256) {
      const int i = j+1 + (f>>6);
      const int k = f & 63;
      if (k > j && k <= i)
        S1[i*68+k] -= S1[i*68+j]*S1[k*68+j]*invd;
    }
  }
  __syncthreads();
  if (t < 64) rdv[t] = rsqrtf(S1[t*68+t]);
  __syncthreads();
  for (int f=t; f<64*64; f+=256) {
    const int i = f>>6, k = f&63;
    if (k < i) S1[i*68+k] *= rdv[k];
  }
  __syncthreads();
  if (t < JD) {
    float w[64];
#pragma unroll
    for (int c=0;c<64;c++) w[c] = W[t*64+c];
#pragma unroll
    for (int c=0;c<64;c++) {
      float v = w[c];
#pragma unroll
      for (int k=0;k<c;k++) v -= w[k]*S1[c*68+k];
      w[c] = v * rdv[c];
    }
#pragma unroll
    for (int c=0;c<64;c++) W[t*64+c] = w[c];
  }
  __syncthreads();
}

// S1(64x64, stride 68) = X^T * Y  (both 192x64 global)
__device__ void dev_hgemm(const float* __restrict__ X, const float* __restrict__ Y,
                          float* S1, float* sla, float* slb, int t) {
  const int ty = t >> 4, tx = t & 15;
  float acc[4][4];
#pragma unroll
  for (int i=0;i<4;i++)
#pragma unroll
    for (int j=0;j<4;j++) acc[i][j]=0.f;
  for (int r0=0; r0<JD; r0+=32) {
    dev_stage_slab(X, sla, r0, t);
    dev_stage_slab(Y, slb, r0, t);
    __syncthreads();
#pragma unroll 4
    for (int rl=0;rl<32;rl++) {
      float va[4], vb[4];
#pragma unroll
      for (int i=0;i<4;i++) va[i] = sla[rl*64 + ty*4+i];
#pragma unroll
      for (int j=0;j<4;j++) vb[j] = slb[rl*64 + tx*4+j];
#pragma unroll
      for (int i=0;i<4;i++)
#pragma unroll
        for (int j=0;j<4;j++) acc[i][j] += va[i]*vb[j];
    }
    __syncthreads();
  }
#pragma unroll
  for (int i=0;i<4;i++)
#pragma unroll
    for (int j=0;j<4;j++)
      S1[(ty*4+i)*68 + tx*4+j] = acc[i][j];
  __syncthreads();
}

// Householder tridiagonalization of A (64x64, stride 68), in place.
// Outputs: a[64] diag, b2[63] squared off-diags. Destroys A.
__device__ void dev_tridiag(float* __restrict__ A, float* a, float* b2,
                            float* vvec, float* wvec, int t) {
  for (int j=0; j<=61; j++) {
    const int m = 63 - j;
    if (t < 64) {
      float xi = (t < m) ? A[j*68 + (j+1+t)] : 0.f;
      float nr = xi*xi;
#pragma unroll
      for (int o=1;o<64;o<<=1) nr += __shfl_xor(nr, o);
      const float sig = sqrtf(nr);
      const float alpha = __shfl(xi, 0);
      const float sgn = (alpha >= 0.f) ? 1.f : -1.f;
      const float v0 = alpha + sgn*sig;
      const float beta = (sig > 1e-20f) ? 1.0f/(sig*fabsf(v0)) : 0.f;
      if (t < m) vvec[t] = (t==0) ? v0 : xi;
      if (t == 0) { a[j] = A[j*68+j]; b2[j] = nr; }
      // p = beta * A_trail * v  (lane t = row)
      float pv = 0.f;
      if (t < m) {
        const float* row = A + (j+1+t)*68 + (j+1);
        for (int c=0;c<m;c++) pv += row[c]*vvec[c];
        pv *= beta;
      }
      float dp = (t<m) ? vvec[t]*pv : 0.f;
#pragma unroll
      for (int o=1;o<64;o<<=1) dp += __shfl_xor(dp, o);
      const float gamma = 0.5f*beta*dp;
      if (t < m) wvec[t] = pv - gamma*vvec[t];
    }
    __syncthreads();
    const int mm = m*m;
    for (int f=t; f<mm; f+=256) {
      const int r = f/m, c = f - r*m;
      A[(j+1+r)*68 + (j+1+c)] -= vvec[r]*wvec[c] + wvec[r]*vvec[c];
    }
    __syncthreads();
  }
  if (t == 0) {
    a[62] = A[62*68+62];
    a[63] = A[63*68+63];
    const float bb = A[62*68+63];
    b2[62] = bb*bb;
  }
  __syncthreads();
}

// Sturm count: #eigenvalues of T strictly below sig
__device__ inline int sturm_cnt(const float* a, const float* b2, float sig) {
  float d = a[0] - sig;
  int n = (d < 0.f) ? 1 : 0;
#pragma unroll 8
  for (int i=1;i<64;i++) {
    const float dd = (fabsf(d) < 1e-20f) ? -1e-20f : d;
    d = (a[i]-sig) - b2[i-1]/dd;
    n += (d < 0.f) ? 1 : 0;
  }
  return n;
}

// Z[r][16g..] = c0*Ax[r][16g..] + c1 * sum_k Xs[r][k]*Bs[k][16g..]
// thread: r = t&63 (row), g = t>>6 (wave-id = 16-col block). stride 68.
__device__ void dev_ns_mm(const float* __restrict__ Xs, const float* __restrict__ Bs,
                          float* __restrict__ Zs, const float* __restrict__ Ax,
                          float c0, float c1, int t) {
  const int r = t & 63;
  const int g = t >> 6;
  float acc[16];
#pragma unroll
  for (int j=0;j<16;j++) acc[j]=0.f;
  const float* xrow = Xs + r*68;
#pragma unroll 2
  for (int kb=0; kb<16; kb++) {
    const float4 av = *(const float4*)(xrow + kb*4);
    const float a4[4] = {av.x, av.y, av.z, av.w};
#pragma unroll
    for (int ki=0; ki<4; ki++) {
      const float* bro = Bs + (kb*4+ki)*68 + g*16;
      const float4 b0 = *(const float4*)(bro+0);
      const float4 b1 = *(const float4*)(bro+4);
      const float4 b2 = *(const float4*)(bro+8);
      const float4 b3 = *(const float4*)(bro+12);
      const float aa = a4[ki];
      acc[0]+=aa*b0.x; acc[1]+=aa*b0.y; acc[2]+=aa*b0.z; acc[3]+=aa*b0.w;
      acc[4]+=aa*b1.x; acc[5]+=aa*b1.y; acc[6]+=aa*b1.z; acc[7]+=aa*b1.w;
      acc[8]+=aa*b2.x; acc[9]+=aa*b2.y; acc[10]+=aa*b2.z; acc[11]+=aa*b2.w;
      acc[12]+=aa*b3.x; acc[13]+=aa*b3.y; acc[14]+=aa*b3.z; acc[15]+=aa*b3.w;
    }
  }
  float* zrow = Zs + r*68 + g*16;
  if (Ax) {
    const float* arow = Ax + r*68 + g*16;
#pragma unroll
    for (int j=0;j<16;j++) zrow[j] = c0*arow[j] + c1*acc[j];
  } else {
#pragma unroll
    for (int j=0;j<16;j++) zrow[j] = acc[j];
  }
}

// B(192x64 global) = W(192x64 global) * P(64x64 LDS stride 68)
__device__ void dev_wp(const float* __restrict__ W, const float* __restrict__ P,
                       float* __restrict__ Bout, int t) {
  const int rg = t >> 2, cg = t & 3;
  float acc[3][16];
#pragma unroll
  for (int i=0;i<3;i++)
#pragma unroll
    for (int j=0;j<16;j++) acc[i][j]=0.f;
  for (int k=0;k<64;k++) {
    const float a0 = W[(rg*3+0)*64 + k];
    const float a1 = W[(rg*3+1)*64 + k];
    const float a2 = W[(rg*3+2)*64 + k];
    const float* pr = P + k*68 + cg*16;
#pragma unroll
    for (int j=0;j<16;j++) {
      const float bb = pr[j];
      acc[0][j] += a0*bb; acc[1][j] += a1*bb; acc[2][j] += a2*bb;
    }
  }
#pragma unroll
  for (int i=0;i<3;i++)
#pragma unroll
    for (int j=0;j<16;j++)
      Bout[(rg*3+i)*64 + cg*16 + j] = acc[i][j];
}

// ---------------------------------------------------------------------------
// K4: per-batch eigen stage. grid 16, 256 threads.
// subspace iter (G16)+CholQR -> H -> tridiag -> Sturm cut -> Newton-Schulz
// sign projector -> M = (W P)(W P)^T
// ---------------------------------------------------------------------------
__global__ __launch_bounds__(256) void k_eig(const float* __restrict__ G16,
                                             const float* __restrict__ Gs,
                                             float* __restrict__ WaG,
                                             float* __restrict__ WbG,
                                             float* __restrict__ Mg) {
  const int b = blockIdx.x;
  const int t = threadIdx.x;
  __shared__ float SH[64*68];     // H -> X0 -> NS ping -> P
  __shared__ float T1[192*33];    // tridiag scratch / NS Y / B-half0
  __shared__ float T2[192*33];    // NS pong / B-half1
  __shared__ float sla[2048];
  __shared__ float slb[2048];
  __shared__ float rdv[64];
  __shared__ float a64[64];
  __shared__ float b2v[64];
  __shared__ float vvec[64];
  __shared__ float wvec[64];
  __shared__ float misc[8];

  const float* G16b = G16 + (size_t)b*JD*JD;
  const float* Gsb  = Gs  + (size_t)b*JD*JD;
  float* cur = WaG + (size_t)b*JD*64;
  float* oth = WbG + (size_t)b*JD*64;
  float* Mb  = Mg  + (size_t)b*JD*JD;

  // ---- stage 1: W = top-64 basis via G16 subspace iteration ----
  for (int f=t; f<JD*64; f+=256)
    cur[f] = G16b[(f>>6)*JD + (f&63)];
  __syncthreads();
  dev_orth(cur, SH, sla, rdv, misc, t, 1e-6f);
  for (int it=0; it<3; it++) {
    dev_matmul(G16b, cur, oth, sla, t);
    dev_orth(oth, SH, sla, rdv, misc, t, 1e-6f);
    float* tmp = cur; cur = oth; oth = tmp;
  }
  dev_orth(cur, SH, sla, rdv, misc, t, 0.f);

  // ---- H = W^T Gs W  -> SH (stride 68) ----
  dev_matmul(Gsb, cur, oth, sla, t);
  dev_hgemm(cur, oth, SH, sla, slb, t);

  // ---- copy H for tridiagonalization ----
  for (int f=t; f<4096; f+=256)
    T1[(f>>6)*68 + (f&63)] = SH[(f>>6)*68 + (f&63)];
  __syncthreads();
  dev_tridiag(T1, a64, b2v, vvec, wvec, t);

  // ---- Sturm bisection for lam1, lam32, lam33, lam64 (wave 0) ----
  if (t < 64) {
    const int i = t;
    const float bl = (i>0)  ? sqrtf(b2v[i-1]) : 0.f;
    const float br = (i<63) ? sqrtf(b2v[i])   : 0.f;
    float lo = a64[i] - bl - br, hi = a64[i] + bl + br;
#pragma unroll
    for (int o=1;o<64;o<<=1) {
      lo = fminf(lo, __shfl_xor(lo,o));
      hi = fmaxf(hi, __shfl_xor(hi,o));
    }
    lo -= 1e-4f; hi += 1e-4f;
    const int g = t >> 4, l = t & 15;
    const int tgt = (g==0) ? 1 : (g==1) ? 32 : (g==2) ? 33 : 64;
    float L = lo, Hh = hi;
    for (int rnd=0; rnd<6; rnd++) {
      const float w = (Hh - L) * (1.0f/17.0f);
      const float sig = L + (l+1)*w;
      const int cnt = sturm_cnt(a64, b2v, sig);
      const unsigned long long bal = __ballot(cnt >= tgt);
      const unsigned int gb = (unsigned int)((bal >> (g*16)) & 0xFFFFull);
      if (gb == 0u) { L = L + 16.f*w; }
      else {
        const int fs = __ffs(gb) - 1;
        Hh = L + (fs+1)*w; L = L + fs*w;
      }
    }
    const float lam = 0.5f*(L+Hh);
    if (l == 0) misc[4+g] = lam;
    if (t == 0) {
      const float mu = 0.5f*(misc[5] + misc[6]);
      float s = fmaxf(misc[7] - mu, mu - misc[4]);
      s = 1.02f*s + 1e-5f;
      misc[1] = mu; misc[2] = 1.0f/s;
    }
  }
  __syncthreads();

  // ---- X0 = (H - mu I)/s ----
  {
    const float mu = misc[1], invs = misc[2];
    for (int f=t; f<4096; f+=256) {
      const int r = f>>6, c = f&63;
      SH[r*68+c] = (SH[r*68+c] - ((r==c) ? mu : 0.f)) * invs;
    }
  }
  __syncthreads();

  // ---- Newton-Schulz sign iteration: X <- 1.5X - 0.5 X^3 ----
  {
    float* Xc = SH;
    float* Zc = T2;
    for (int it=0; it<28; it++) {
      dev_ns_mm(Xc, Xc, T1, nullptr, 0.f, 1.f, t);      // Y = X^2
      __syncthreads();
      dev_ns_mm(Xc, T1, Zc, Xc, 1.5f, -0.5f, t);        // Z = 1.5X - 0.5 X*Y
      __syncthreads();
      float* tmp = Xc; Xc = Zc; Zc = tmp;
    }
    // 28 swaps (even) -> X back in SH
  }
  // ---- P = (X + I)/2 (rank-32 projector) ----
  for (int f=t; f<4096; f+=256) {
    const int r = f>>6, c = f&63;
    SH[r*68+c] = 0.5f*SH[r*68+c] + ((r==c) ? 0.5f : 0.f);
  }
  __syncthreads();

  // ---- B = W * P -> global (oth) ----
  dev_wp(cur, SH, oth, t);
  __syncthreads();

  // ---- M = B B^T ----
  for (int f=t; f<JD*32; f+=256) {
    const int r = f>>5, c = f&31;
    T1[r*33+c] = oth[r*64+c];
    T2[r*33+c] = oth[r*64+32+c];
  }
  __syncthreads();
  for (int tt=t; tt<576; tt+=256) {
    const int tr = tt/24, tc = tt - tr*24;
    const int r0 = tr*8, c0 = tc*8;
    float acc2[8][8];
#pragma unroll
    for (int i=0;i<8;i++)
#pragma unroll
      for (int j=0;j<8;j++) acc2[i][j]=0.f;
    for (int k=0;k<32;k++) {
      float va[8], vb[8];
#pragma unroll
      for (int i=0;i<8;i++) va[i] = T1[(r0+i)*33+k];
#pragma unroll
      for (int j=0;j<8;j++) vb[j] = T1[(c0+j)*33+k];
#pragma unroll
      for (int i=0;i<8;i++)
#pragma unroll
        for (int j=0;j<8;j++) acc2[i][j] += va[i]*vb[j];
    }
    for (int k=0;k<32;k++) {
      float va[8], vb[8];
#pragma unroll
      for (int i=0;i<8;i++) va[i] = T2[(r0+i)*33+k];
#pragma unroll
      for (int j=0;j<8;j++) vb[j] = T2[(c0+j)*33+k];
#pragma unroll
      for (int i=0;i<8;i++)
#pragma unroll
        for (int j=0;j<8;j++) acc2[i][j] += va[i]*vb[j];
    }
#pragma unroll
    for (int i=0;i<8;i++)
#pragma unroll
      for (int j=0;j<8;j++)
        Mb[(r0+i)*JD + c0+j] = acc2[i][j];
  }
}

// ---------------------------------------------------------------------------
// K5: recon = A * M, fused depatchify. grid (128 patch-blocks, 16 batches).
// ---------------------------------------------------------------------------
__global__ __launch_bounds__(256) void k_recon(const float* __restrict__ x,
                                               const float* __restrict__ Mg,
                                               float* __restrict__ out) {
  const int nb = blockIdx.x;
  const int b  = blockIdx.y;
  const int t  = threadIdx.x;
  __shared__ float At[32][17];
  __shared__ float Mt[16][JD];
  const float* xb = x + (size_t)b*3*IMG*IMG;
  const float* Mb = Mg + (size_t)b*JD*JD;
  float* ob = out + (size_t)b*3*IMG*IMG;
  const int pg = t >> 4;
  const int jg = t & 15;
  float acc[2][12];
#pragma unroll
  for (int i=0;i<2;i++)
#pragma unroll
    for (int j=0;j<12;j++) acc[i][j]=0.f;
  for (int j0=0; j0<JD; j0+=16) {
    for (int f=t; f<512; f+=256) {
      const int nl = f >> 4, jj = f & 15;
      const int j = j0 + jj;
      const int n = nb*32 + nl;
      const int hh = n >> 6, ww = n & 63;
      const int c = j >> 6, p = (j >> 3) & 7, q = j & 7;
      At[nl][jj] = xb[(c*IMG + hh*8+p)*IMG + ww*8 + q];
    }
    for (int f=t; f<3072; f+=256) {
      const int jj = f / JD, cc = f - jj*JD;
      Mt[jj][cc] = Mb[(j0+jj)*JD + cc];
    }
    __syncthreads();
#pragma unroll 4
    for (int jj=0;jj<16;jj++) {
      const float a0 = At[pg*2+0][jj];
      const float a1 = At[pg*2+1][jj];
#pragma unroll
      for (int j=0;j<12;j++) {
        const float mm = Mt[jj][jg*12+j];
        acc[0][j] += a0*mm;
        acc[1][j] += a1*mm;
      }
    }
    __syncthreads();
  }
#pragma unroll
  for (int i=0;i<2;i++) {
    const int n = nb*32 + pg*2 + i;
    const int hh = n >> 6, ww = n & 63;
#pragma unroll
    for (int j4=0;j4<3;j4++) {
      const int jo = jg*12 + j4*4;
      const int c = jo >> 6, p = (jo >> 3) & 7, q = jo & 7;
      const float4 v = make_float4(acc[i][j4*4+0], acc[i][j4*4+1],
                                   acc[i][j4*4+2], acc[i][j4*4+3]);
      *(float4*)(ob + (size_t)(c*IMG + hh*8+p)*IMG + ww*8 + q) = v;
    }
  }
}

// ---------------------------------------------------------------------------
extern "C" void kernel_launch(void* const* d_in, const int* in_sizes, int n_in,
                              void* d_out, int out_size, void* d_ws, size_t ws_size,
                              hipStream_t stream) {
  (void)in_sizes; (void)n_in; (void)out_size; (void)ws_size;
  const float* x = (const float*)d_in[0];
  float* out = (float*)d_out;
  float* ws  = (float*)d_ws;

  float* part = ws;
  float* Gs   = ws + 2359296;
  float* P0   = ws + 2949120;
  float* P1   = ws + 3538944;
  float* Mg   = ws;             // overlay (part dead after k_greduce)
  float* Wa   = ws + 589824;
  float* Wb   = ws + 786432;

  k_gram  <<<dim3(4,4,16), 256, 0, stream>>>(x, part);
  k_greduce<<<2304,        256, 0, stream>>>(part, Gs);
  k_sq    <<<dim3(6,16),   256, 0, stream>>>(Gs, P0);   // Gs^2
  k_sq    <<<dim3(6,16),   256, 0, stream>>>(P0, P1);   // Gs^4
  k_sq    <<<dim3(6,16),   256, 0, stream>>>(P1, P0);   // Gs^8
  k_sq    <<<dim3(6,16),   256, 0, stream>>>(P0, P1);   // Gs^16
  k_eig   <<<16,           256, 0, stream>>>(P1, Gs, Wa, Wb, Mg);
  k_recon <<<dim3(128,16), 256, 0, stream>>>(x, Mg, out);
}

// Round 3
// 1254.099 us; speedup vs baseline: 1.4880x; 1.1078x over previous
//
#include <hip/hip_runtime.h>
#include <cstdint>
#include <cstddef>

#define IMG 512
#define JD 192

// ---------------------------------------------------------------------------
// K1: partial Gram. grid (4 patch-chunks, 4 row-slabs, 16 batches), 256 thr.
// ---------------------------------------------------------------------------
__global__ __launch_bounds__(256) void k_gram(const float* __restrict__ x,
                                              float* __restrict__ part) {
  const int ck = blockIdx.x;
  const int sl = blockIdx.y;
  const int b  = blockIdx.z;
  const int t  = threadIdx.x;
  __shared__ float tile[32][JD];
  const int ty = t >> 5;
  const int tx = t & 31;
  const int r0 = sl*48 + ty*6;
  const int c0 = tx*6;
  float acc[6][6];
#pragma unroll
  for (int i=0;i<6;i++)
#pragma unroll
    for (int j=0;j<6;j++) acc[i][j]=0.f;
  const float* xb = x + (size_t)b*3*IMG*IMG;
  const int nbeg = ck*1024;
  for (int n0 = nbeg; n0 < nbeg+1024; n0 += 32) {
    for (int f = t; f < 32*JD; f += 256) {
      const int nl = f / JD, j = f - nl*JD;
      const int n = n0 + nl;
      const int hh = n >> 6, ww = n & 63;
      const int c = j >> 6, p = (j >> 3) & 7, q = j & 7;
      tile[nl][j] = xb[(c*IMG + hh*8+p)*IMG + ww*8 + q];
    }
    __syncthreads();
#pragma unroll 4
    for (int nl = 0; nl < 32; nl++) {
      float va[6], vb[6];
#pragma unroll
      for (int i=0;i<6;i++) va[i] = tile[nl][r0+i];
#pragma unroll
      for (int j=0;j<6;j++) vb[j] = tile[nl][c0+j];
#pragma unroll
      for (int i=0;i<6;i++)
#pragma unroll
        for (int j=0;j<6;j++) acc[i][j] += va[i]*vb[j];
    }
    __syncthreads();
  }
  float* dst = part + (((size_t)(b*4 + sl))*4 + ck) * (size_t)(48*JD);
#pragma unroll
  for (int i=0;i<6;i++)
#pragma unroll
    for (int j=0;j<6;j++)
      dst[(ty*6+i)*JD + c0+j] = acc[i][j];
}

// ---------------------------------------------------------------------------
// K2: reduce 4 chunk-partials -> Gs = G / 4096
// ---------------------------------------------------------------------------
__global__ __launch_bounds__(256) void k_greduce(const float* __restrict__ part,
                                                 float* __restrict__ Gs) {
  const int idx = blockIdx.x*256 + threadIdx.x;
  const int b = idx / (JD*JD);
  const int e = idx - b*(JD*JD);
  const int r = e / JD;
  const int sl = r / 48;
  const int w = (r - sl*48)*JD + (e - r*JD);
  const float* p = part + ((size_t)(b*4+sl))*4*(48*JD) + w;
  float s = 0.f;
#pragma unroll
  for (int ck=0; ck<4; ck++) s += p[(size_t)ck*48*JD];
  Gs[idx] = s * (1.0f/4096.0f);
}

// ---------------------------------------------------------------------------
// K3: D = S*S for symmetric S (per batch), lower-tri tile pairs.
// ---------------------------------------------------------------------------
__global__ __launch_bounds__(256) void k_sq(const float* __restrict__ S,
                                            float* __restrict__ D) {
  const int tp = blockIdx.x;
  const int b  = blockIdx.y;
  int ti, tj;
  if      (tp==0){ti=0;tj=0;} else if (tp==1){ti=1;tj=0;}
  else if (tp==2){ti=1;tj=1;} else if (tp==3){ti=2;tj=0;}
  else if (tp==4){ti=2;tj=1;} else            {ti=2;tj=2;}
  const float* Sb = S + (size_t)b*JD*JD;
  float* Db = D + (size_t)b*JD*JD;
  __shared__ float Ar[64][33];
  __shared__ float Br[64][33];
  const int t = threadIdx.x;
  const int ty = t >> 4, tx = t & 15;
  float acc[4][4];
#pragma unroll
  for (int i=0;i<4;i++)
#pragma unroll
    for (int j=0;j<4;j++) acc[i][j]=0.f;
  for (int k0=0; k0<JD; k0+=32) {
    for (int f=t; f<2048; f+=256) {
      const int row = f >> 5, kk = f & 31;
      Ar[row][kk] = Sb[(ti*64+row)*JD + k0+kk];
      Br[row][kk] = Sb[(tj*64+row)*JD + k0+kk];
    }
    __syncthreads();
#pragma unroll 4
    for (int k=0;k<32;k++) {
      float va[4], vb[4];
#pragma unroll
      for (int i=0;i<4;i++) va[i] = Ar[ty*4+i][k];
#pragma unroll
      for (int j=0;j<4;j++) vb[j] = Br[tx*4+j][k];
#pragma unroll
      for (int i=0;i<4;i++)
#pragma unroll
        for (int j=0;j<4;j++) acc[i][j] += va[i]*vb[j];
    }
    __syncthreads();
  }
#pragma unroll
  for (int i=0;i<4;i++)
#pragma unroll
    for (int j=0;j<4;j++) {
      const int r = ti*64+ty*4+i, c = tj*64+tx*4+j;
      Db[r*JD+c] = acc[i][j];
      if (ti != tj) Db[c*JD+r] = acc[i][j];
    }
}

// ---------------------------------------------------------------------------
// K4 helpers (per-batch block, 256 threads)
// ---------------------------------------------------------------------------
__device__ inline void dev_stage_slab(const float* __restrict__ src, float* sl,
                                      int base, int t) {
  for (int f = t; f < 2048; f += 256) sl[f] = src[(base + (f>>6))*64 + (f&63)];
}

// Wout(192x64) = G(192x192) * Win(192x64)
__device__ void dev_matmul(const float* __restrict__ G, const float* __restrict__ Win,
                           float* __restrict__ Wout, float* sla, int t) {
  const int rg = t >> 2, cg = t & 3;
  float acc[3][16];
#pragma unroll
  for (int i=0;i<3;i++)
#pragma unroll
    for (int j=0;j<16;j++) acc[i][j]=0.f;
  for (int k0=0; k0<JD; k0+=32) {
    dev_stage_slab(Win, sla, k0, t);
    __syncthreads();
#pragma unroll 4
    for (int k=0;k<32;k++) {
      const float a0 = G[(rg*3+0)*JD + k0+k];
      const float a1 = G[(rg*3+1)*JD + k0+k];
      const float a2 = G[(rg*3+2)*JD + k0+k];
#pragma unroll
      for (int j=0;j<16;j++) {
        const float bb = sla[k*64 + cg*16 + j];
        acc[0][j] += a0*bb; acc[1][j] += a1*bb; acc[2][j] += a2*bb;
      }
    }
    __syncthreads();
  }
#pragma unroll
  for (int i=0;i<3;i++)
#pragma unroll
    for (int j=0;j<16;j++)
      Wout[(rg*3+i)*64 + cg*16 + j] = acc[i][j];
  __syncthreads();
}

// In-place ridge-CholQR of W (192x64). S1 is 64x68 LDS scratch.
__device__ void dev_orth(float* __restrict__ W, float* S1, float* sla,
                         float* rdv, float* misc, int t, float ridge) {
  const int ty = t >> 4, tx = t & 15;
  float acc[4][4];
#pragma unroll
  for (int i=0;i<4;i++)
#pragma unroll
    for (int j=0;j<4;j++) acc[i][j]=0.f;
  for (int r0=0; r0<JD; r0+=32) {
    dev_stage_slab(W, sla, r0, t);
    __syncthreads();
#pragma unroll 4
    for (int rl=0;rl<32;rl++) {
      const float4 va4 = *(const float4*)(sla + rl*64 + ty*4);
      const float4 vb4 = *(const float4*)(sla + rl*64 + tx*4);
      const float a4[4] = {va4.x, va4.y, va4.z, va4.w};
      const float b4[4] = {vb4.x, vb4.y, vb4.z, vb4.w};
#pragma unroll
      for (int i=0;i<4;i++)
#pragma unroll
        for (int j=0;j<4;j++) acc[i][j] += a4[i]*b4[j];
    }
    __syncthreads();
  }
#pragma unroll
  for (int i=0;i<4;i++)
#pragma unroll
    for (int j=0;j<4;j++)
      S1[(ty*4+i)*68 + tx*4+j] = acc[i][j];
  __syncthreads();
  if (ridge > 0.f) {
    if (t == 0) {
      float m = 0.f;
      for (int j=0;j<64;j++) m = fmaxf(m, S1[j*68+j]);
      misc[0] = m * ridge;
    }
    __syncthreads();
    if (t < 64) S1[t*68+t] += misc[0];
    __syncthreads();
  }
  for (int j=0;j<63;j++) {
    __syncthreads();
    const float invd = 1.0f / S1[j*68+j];
    const int wd = 63 - j;
    for (int f=t; f<wd*64; f+=256) {
      const int i = j+1 + (f>>6);
      const int k = f & 63;
      if (k > j && k <= i)
        S1[i*68+k] -= S1[i*68+j]*S1[k*68+j]*invd;
    }
  }
  __syncthreads();
  if (t < 64) rdv[t] = rsqrtf(S1[t*68+t]);
  __syncthreads();
  for (int f=t; f<64*64; f+=256) {
    const int i = f>>6, k = f&63;
    if (k < i) S1[i*68+k] *= rdv[k];
  }
  __syncthreads();
  if (t < JD) {
    float w[64];
#pragma unroll
    for (int c=0;c<64;c++) w[c] = W[t*64+c];
#pragma unroll
    for (int c=0;c<64;c++) {
      float v = w[c];
#pragma unroll
      for (int k=0;k<c;k++) v -= w[k]*S1[c*68+k];
      w[c] = v * rdv[c];
    }
#pragma unroll
    for (int c=0;c<64;c++) W[t*64+c] = w[c];
  }
  __syncthreads();
}

// S1(64x64, stride 68) = X^T * Y  (both 192x64 global)
__device__ void dev_hgemm(const float* __restrict__ X, const float* __restrict__ Y,
                          float* S1, float* sla, float* slb, int t) {
  const int ty = t >> 4, tx = t & 15;
  float acc[4][4];
#pragma unroll
  for (int i=0;i<4;i++)
#pragma unroll
    for (int j=0;j<4;j++) acc[i][j]=0.f;
  for (int r0=0; r0<JD; r0+=32) {
    dev_stage_slab(X, sla, r0, t);
    dev_stage_slab(Y, slb, r0, t);
    __syncthreads();
#pragma unroll 4
    for (int rl=0;rl<32;rl++) {
      const float4 va4 = *(const float4*)(sla + rl*64 + ty*4);
      const float4 vb4 = *(const float4*)(slb + rl*64 + tx*4);
      const float a4[4] = {va4.x, va4.y, va4.z, va4.w};
      const float b4[4] = {vb4.x, vb4.y, vb4.z, vb4.w};
#pragma unroll
      for (int i=0;i<4;i++)
#pragma unroll
        for (int j=0;j<4;j++) acc[i][j] += a4[i]*b4[j];
    }
    __syncthreads();
  }
#pragma unroll
  for (int i=0;i<4;i++)
#pragma unroll
    for (int j=0;j<4;j++)
      S1[(ty*4+i)*68 + tx*4+j] = acc[i][j];
  __syncthreads();
}

// Householder tridiag of A (64x64, stride 68) in place; keeps reflector tails
// in the rows of A (row j, cols j+1.. = v components, v0 replaced separately).
// Outputs: a[64] diag, b2[63] off-diag^2, bsg[63] signed off-diag,
//          v0s[62] v0 values, bts[62] beta values.
__device__ void dev_tridiag(float* __restrict__ A, float* a, float* b2,
                            float* bsg, float* v0s, float* bts,
                            float* vvec, float* wvec, int t) {
  for (int j=0; j<=61; j++) {
    const int m = 63 - j;
    if (t < 64) {
      float xi = (t < m) ? A[j*68 + (j+1+t)] : 0.f;
      float nr = xi*xi;
#pragma unroll
      for (int o=1;o<64;o<<=1) nr += __shfl_xor(nr, o);
      const float sig = sqrtf(nr);
      const float alpha = __shfl(xi, 0);
      const float sgn = (alpha >= 0.f) ? 1.f : -1.f;
      const float v0 = alpha + sgn*sig;
      const float beta = (sig > 1e-20f) ? 1.0f/(sig*fabsf(v0)) : 0.f;
      if (t < m) vvec[t] = (t==0) ? v0 : xi;
      if (t == 0) {
        a[j] = A[j*68+j]; b2[j] = nr; bsg[j] = -sgn*sig;
        v0s[j] = v0; bts[j] = beta;
      }
      float pv = 0.f;
      if (t < m) {
        const float* row = A + (j+1+t)*68 + (j+1);
        for (int c=0;c<m;c++) pv += row[c]*vvec[c];
        pv *= beta;
      }
      float dp = (t<m) ? vvec[t]*pv : 0.f;
#pragma unroll
      for (int o=1;o<64;o<<=1) dp += __shfl_xor(dp, o);
      const float gamma = 0.5f*beta*dp;
      if (t < m) wvec[t] = pv - gamma*vvec[t];
    }
    __syncthreads();
    const int mm = m*m;
    for (int f=t; f<mm; f+=256) {
      const int r = f/m, c = f - r*m;
      A[(j+1+r)*68 + (j+1+c)] -= vvec[r]*wvec[c] + wvec[r]*vvec[c];
    }
    __syncthreads();
  }
  if (t == 0) {
    a[62] = A[62*68+62];
    a[63] = A[63*68+63];
    const float bb = A[62*68+63];
    b2[62] = bb*bb;
    bsg[62] = bb;
  }
  __syncthreads();
}

// Sturm count: #eigenvalues of T strictly below sig
__device__ inline int sturm_cnt(const float* a, const float* b2, float sig) {
  float d = a[0] - sig;
  int n = (d < 0.f) ? 1 : 0;
#pragma unroll 8
  for (int i=1;i<64;i++) {
    const float dd = (fabsf(d) < 1e-20f) ? -1e-20f : d;
    d = (a[i]-sig) - b2[i-1]/dd;
    n += (d < 0.f) ? 1 : 0;
  }
  return n;
}

__device__ inline float dguard(float d) {
  if (fabsf(d) < 1e-12f) return (d < 0.f) ? -1e-12f : 1e-12f;
  return d;
}

// ---------------------------------------------------------------------------
// K4: per-batch eigen stage. grid 16, 256 threads.
// subspace iter (G16)+CholQR -> H -> tridiag -> per-eig bisection ->
// twisted inverse iteration -> CholQR32 -> Householder backtransform ->
// B = W*V -> M = B B^T
// ---------------------------------------------------------------------------
__global__ __launch_bounds__(256) void k_eig(const float* __restrict__ G16,
                                             const float* __restrict__ Gs,
                                             float* __restrict__ WaG,
                                             float* __restrict__ WbG,
                                             float* __restrict__ Mg) {
  const int b = blockIdx.x;
  const int t = threadIdx.x;
  __shared__ float SH[64*68];      // orth scratch -> H -> reflector storage
  __shared__ float sla[2048];
  __shared__ float slb[2048];
  __shared__ float Vt[64*36];      // T-eigenvectors -> backtransformed V (64x32)
  __shared__ float dpA[64*33];     // d+ table; later CholQR32 Gram
  __shared__ float dmA[64*33];     // d- table
  __shared__ float Bt[32*196];     // B^T staging (32 x 192)
  __shared__ float ps[8*33];
  __shared__ float wvred[32];
  __shared__ float rdv[64];
  __shared__ float a64[64];
  __shared__ float b2v[64];
  __shared__ float bsg[64];
  __shared__ float v0s[64];
  __shared__ float bts[64];
  __shared__ float vvec[64];
  __shared__ float wvec[64];
  __shared__ float lam[32];
  __shared__ float misc[8];

  const float* G16b = G16 + (size_t)b*JD*JD;
  const float* Gsb  = Gs  + (size_t)b*JD*JD;
  float* cur = WaG + (size_t)b*JD*64;
  float* oth = WbG + (size_t)b*JD*64;
  float* Mb  = Mg  + (size_t)b*JD*JD;

  // ---- stage 1: W = top-64 basis via G16 subspace iteration (3 mm, 4 orth) ----
  for (int f=t; f<JD*64; f+=256)
    cur[f] = G16b[(f>>6)*JD + (f&63)];
  __syncthreads();
  for (int it=0; it<3; it++) {
    dev_matmul(G16b, cur, oth, sla, t);
    dev_orth(oth, SH, sla, rdv, misc, t, 1e-6f);
    float* tmp = cur; cur = oth; oth = tmp;
  }
  dev_orth(cur, SH, sla, rdv, misc, t, 0.f);   // CholQR pass 2 (clean)

  // ---- H = W^T Gs W  -> SH (stride 68) ----
  dev_matmul(Gsb, cur, oth, sla, t);
  dev_hgemm(cur, oth, SH, sla, slb, t);

  // ---- tridiagonalize H in place (keeps reflectors in SH rows) ----
  dev_tridiag(SH, a64, b2v, bsg, v0s, bts, vvec, wvec, t);

  // ---- spectrum bounds (Gershgorin) ----
  if (t < 64) {
    const float bl = (t>0)  ? sqrtf(b2v[t-1]) : 0.f;
    const float br = (t<63) ? sqrtf(b2v[t])   : 0.f;
    float lo = a64[t] - bl - br, hi = a64[t] + bl + br;
#pragma unroll
    for (int o=1;o<64;o<<=1) {
      lo = fminf(lo, __shfl_xor(lo,o));
      hi = fmaxf(hi, __shfl_xor(hi,o));
    }
    if (t == 0) { misc[0] = lo - 1e-4f; misc[1] = hi + 1e-4f; }
  }
  __syncthreads();

  // ---- per-eigenvalue bisection: lane l -> ascending index 32+l ----
  if (t < 32) {
    const int r = 32 + t;
    float L = misc[0], H = misc[1];
    for (int it=0; it<30; it++) {
      const float mid = 0.5f*(L+H);
      const int cnt = sturm_cnt(a64, b2v, mid);
      if (cnt <= r) L = mid; else H = mid;
    }
    lam[t] = 0.5f*(L+H);
  }
  __syncthreads();

  // ---- twisted-factorization inverse iteration (lane l = one eigvec) ----
  if (t < 32) {
    const int l = t;
    const float lm = lam[l];
    float d = dguard(a64[0] - lm);
    dpA[0*33+l] = d;
    for (int i=1;i<64;i++) {
      d = dguard((a64[i]-lm) - b2v[i-1]/d);
      dpA[i*33+l] = d;
    }
    float e = dguard(a64[63] - lm);
    dmA[63*33+l] = e;
    for (int i=62;i>=0;i--) {
      e = dguard((a64[i]-lm) - b2v[i]/e);
      dmA[i*33+l] = e;
    }
    int ks = 0; float gbest = 1e30f;
    for (int i=0;i<64;i++) {
      const float g = fabsf(dpA[i*33+l] + dmA[i*33+l] - (a64[i]-lm));
      if (g < gbest) { gbest = g; ks = i; }
    }
    Vt[ks*36+l] = 1.f;
    float z = 1.f;
    for (int i=ks-1;i>=0;i--) {
      z = -(bsg[i]*z) / dpA[i*33+l];
      z = fminf(fmaxf(z, -1e18f), 1e18f);
      Vt[i*36+l] = z;
    }
    z = 1.f;
    for (int i=ks+1;i<64;i++) {
      z = -(bsg[i-1]*z) / dmA[i*33+l];
      z = fminf(fmaxf(z, -1e18f), 1e18f);
      Vt[i*36+l] = z;
    }
    float nr2 = 0.f;
    for (int i=0;i<64;i++) { const float zz = Vt[i*36+l]; nr2 += zz*zz; }
    const float inv = rsqrtf(nr2);
    for (int i=0;i<64;i++) Vt[i*36+l] *= inv;
  }
  __syncthreads();

  // ---- CholQR-32 safety pass on Vt (fixes near-degenerate pairs) ----
  for (int f=t; f<1024; f+=256) {
    const int i = f>>5, j = f&31;
    float s = 0.f;
    for (int r=0;r<64;r++) s += Vt[r*36+i]*Vt[r*36+j];
    dpA[i*33+j] = s;
  }
  __syncthreads();
  if (t == 0) {
    float m = 0.f;
    for (int j=0;j<32;j++) m = fmaxf(m, dpA[j*33+j]);
    misc[2] = m * 1e-7f;
  }
  __syncthreads();
  if (t < 32) dpA[t*33+t] += misc[2];
  for (int j=0;j<31;j++) {
    __syncthreads();
    const float invd = 1.0f / dpA[j*33+j];
    for (int f=t; f<(31-j)*32; f+=256) {
      const int i = j+1 + (f>>5);
      const int k = f & 31;
      if (k > j && k <= i)
        dpA[i*33+k] -= dpA[i*33+j]*dpA[k*33+j]*invd;
    }
  }
  __syncthreads();
  if (t < 32) rdv[t] = rsqrtf(dpA[t*33+t]);
  __syncthreads();
  for (int f=t; f<1024; f+=256) {
    const int i = f>>5, k = f&31;
    if (k < i) dpA[i*33+k] *= rdv[k];
  }
  __syncthreads();
  if (t < 64) {
    float w[32];
#pragma unroll
    for (int c=0;c<32;c++) w[c] = Vt[t*36+c];
#pragma unroll
    for (int c=0;c<32;c++) {
      float v = w[c];
#pragma unroll
      for (int k=0;k<c;k++) v -= w[k]*dpA[c*33+k];
      w[c] = v * rdv[c];
    }
#pragma unroll
    for (int c=0;c<32;c++) Vt[t*36+c] = w[c];
  }
  __syncthreads();

  // ---- backtransform: V = H_0 H_1 ... H_61 Vt ----
  for (int j=61; j>=0; j--) {
    const int m = 63 - j;
    {
      const int c = t & 31, g = t >> 5;
      float s = 0.f;
      for (int r=g; r<m; r+=8) {
        const float vr = (r==0) ? v0s[j] : SH[j*68 + (j+1+r)];
        s += vr * Vt[(j+1+r)*36 + c];
      }
      ps[g*33+c] = s;
    }
    __syncthreads();
    if (t < 32) {
      float s = 0.f;
#pragma unroll
      for (int g=0;g<8;g++) s += ps[g*33+t];
      wvred[t] = s * bts[j];
    }
    __syncthreads();
    {
      const int c = t & 31, g = t >> 5;
      for (int r=g; r<m; r+=8) {
        const float vr = (r==0) ? v0s[j] : SH[j*68 + (j+1+r)];
        Vt[(j+1+r)*36 + c] -= vr * wvred[c];
      }
    }
    __syncthreads();
  }

  // ---- B^T = (W * V)^T  -> Bt (32 x 192, stride 196) ----
  if (t < JD) {
    float accv[32];
#pragma unroll
    for (int c=0;c<32;c++) accv[c] = 0.f;
    const float4* crow = (const float4*)(cur + t*64);
#pragma unroll 2
    for (int kb=0; kb<16; kb++) {
      const float4 av = crow[kb];
      const float a4[4] = {av.x, av.y, av.z, av.w};
#pragma unroll
      for (int ki=0; ki<4; ki++) {
        const float aa = a4[ki];
        const float* vrow = Vt + (kb*4+ki)*36;
        const float4 v0 = *(const float4*)(vrow+0);
        const float4 v1 = *(const float4*)(vrow+4);
        const float4 v2 = *(const float4*)(vrow+8);
        const float4 v3 = *(const float4*)(vrow+12);
        const float4 v4 = *(const float4*)(vrow+16);
        const float4 v5 = *(const float4*)(vrow+20);
        const float4 v6 = *(const float4*)(vrow+24);
        const float4 v7 = *(const float4*)(vrow+28);
        accv[0]+=aa*v0.x; accv[1]+=aa*v0.y; accv[2]+=aa*v0.z; accv[3]+=aa*v0.w;
        accv[4]+=aa*v1.x; accv[5]+=aa*v1.y; accv[6]+=aa*v1.z; accv[7]+=aa*v1.w;
        accv[8]+=aa*v2.x; accv[9]+=aa*v2.y; accv[10]+=aa*v2.z; accv[11]+=aa*v2.w;
        accv[12]+=aa*v3.x; accv[13]+=aa*v3.y; accv[14]+=aa*v3.z; accv[15]+=aa*v3.w;
        accv[16]+=aa*v4.x; accv[17]+=aa*v4.y; accv[18]+=aa*v4.z; accv[19]+=aa*v4.w;
        accv[20]+=aa*v5.x; accv[21]+=aa*v5.y; accv[22]+=aa*v5.z; accv[23]+=aa*v5.w;
        accv[24]+=aa*v6.x; accv[25]+=aa*v6.y; accv[26]+=aa*v6.z; accv[27]+=aa*v6.w;
        accv[28]+=aa*v7.x; accv[29]+=aa*v7.y; accv[30]+=aa*v7.z; accv[31]+=aa*v7.w;
      }
    }
#pragma unroll
    for (int c=0;c<32;c++) Bt[c*196 + t] = accv[c];
  }
  __syncthreads();

  // ---- M = B B^T (192x192) -> global ----
  for (int tt=t; tt<576; tt+=256) {
    const int tr = tt/24, tc = tt - tr*24;
    const int r0 = tr*8, c0 = tc*8;
    float acc2[8][8];
#pragma unroll
    for (int i=0;i<8;i++)
#pragma unroll
      for (int j=0;j<8;j++) acc2[i][j]=0.f;
    for (int k=0;k<32;k++) {
      const float* br = Bt + k*196;
      const float4 a0 = *(const float4*)(br + r0);
      const float4 a1 = *(const float4*)(br + r0 + 4);
      const float4 b0 = *(const float4*)(br + c0);
      const float4 b1 = *(const float4*)(br + c0 + 4);
      const float va[8] = {a0.x,a0.y,a0.z,a0.w,a1.x,a1.y,a1.z,a1.w};
      const float vb[8] = {b0.x,b0.y,b0.z,b0.w,b1.x,b1.y,b1.z,b1.w};
#pragma unroll
      for (int i=0;i<8;i++)
#pragma unroll
        for (int j=0;j<8;j++) acc2[i][j] += va[i]*vb[j];
    }
#pragma unroll
    for (int i=0;i<8;i++)
#pragma unroll
      for (int j=0;j<8;j++)
        Mb[(r0+i)*JD + c0+j] = acc2[i][j];
  }
}

// ---------------------------------------------------------------------------
// K5: recon = A * M, fused depatchify. grid (128 patch-blocks, 16 batches).
// ---------------------------------------------------------------------------
__global__ __launch_bounds__(256) void k_recon(const float* __restrict__ x,
                                               const float* __restrict__ Mg,
                                               float* __restrict__ out) {
  const int nb = blockIdx.x;
  const int b  = blockIdx.y;
  const int t  = threadIdx.x;
  __shared__ float At[32][17];
  __shared__ float Mt[16][JD];
  const float* xb = x + (size_t)b*3*IMG*IMG;
  const float* Mb = Mg + (size_t)b*JD*JD;
  float* ob = out + (size_t)b*3*IMG*IMG;
  const int pg = t >> 4;
  const int jg = t & 15;
  float acc[2][12];
#pragma unroll
  for (int i=0;i<2;i++)
#pragma unroll
    for (int j=0;j<12;j++) acc[i][j]=0.f;
  for (int j0=0; j0<JD; j0+=16) {
    for (int f=t; f<512; f+=256) {
      const int nl = f >> 4, jj = f & 15;
      const int j = j0 + jj;
      const int n = nb*32 + nl;
      const int hh = n >> 6, ww = n & 63;
      const int c = j >> 6, p = (j >> 3) & 7, q = j & 7;
      At[nl][jj] = xb[(c*IMG + hh*8+p)*IMG + ww*8 + q];
    }
    for (int f=t; f<3072; f+=256) {
      const int jj = f / JD, cc = f - jj*JD;
      Mt[jj][cc] = Mb[(j0+jj)*JD + cc];
    }
    __syncthreads();
#pragma unroll 4
    for (int jj=0;jj<16;jj++) {
      const float a0 = At[pg*2+0][jj];
      const float a1 = At[pg*2+1][jj];
#pragma unroll
      for (int j=0;j<12;j++) {
        const float mm = Mt[jj][jg*12+j];
        acc[0][j] += a0*mm;
        acc[1][j] += a1*mm;
      }
    }
    __syncthreads();
  }
#pragma unroll
  for (int i=0;i<2;i++) {
    const int n = nb*32 + pg*2 + i;
    const int hh = n >> 6, ww = n & 63;
#pragma unroll
    for (int j4=0;j4<3;j4++) {
      const int jo = jg*12 + j4*4;
      const int c = jo >> 6, p = (jo >> 3) & 7, q = jo & 7;
      const float4 v = make_float4(acc[i][j4*4+0], acc[i][j4*4+1],
                                   acc[i][j4*4+2], acc[i][j4*4+3]);
      *(float4*)(ob + (size_t)(c*IMG + hh*8+p)*IMG + ww*8 + q) = v;
    }
  }
}

// ---------------------------------------------------------------------------
extern "C" void kernel_launch(void* const* d_in, const int* in_sizes, int n_in,
                              void* d_out, int out_size, void* d_ws, size_t ws_size,
                              hipStream_t stream) {
  (void)in_sizes; (void)n_in; (void)out_size; (void)ws_size;
  const float* x = (const float*)d_in[0];
  float* out = (float*)d_out;
  float* ws  = (float*)d_ws;

  float* part = ws;
  float* Gs   = ws + 2359296;
  float* P0   = ws + 2949120;
  float* P1   = ws + 3538944;
  float* Mg   = ws;             // overlay (part dead after k_greduce)
  float* Wa   = ws + 589824;
  float* Wb   = ws + 786432;

  k_gram  <<<dim3(4,4,16), 256, 0, stream>>>(x, part);
  k_greduce<<<2304,        256, 0, stream>>>(part, Gs);
  k_sq    <<<dim3(6,16),   256, 0, stream>>>(Gs, P0);   // Gs^2
  k_sq    <<<dim3(6,16),   256, 0, stream>>>(P0, P1);   // Gs^4
  k_sq    <<<dim3(6,16),   256, 0, stream>>>(P1, P0);   // Gs^8
  k_sq    <<<dim3(6,16),   256, 0, stream>>>(P0, P1);   // Gs^16
  k_eig   <<<16,           256, 0, stream>>>(P1, Gs, Wa, Wb, Mg);
  k_recon <<<dim3(128,16), 256, 0, stream>>>(x, Mg, out);
}